// Round 4
// baseline (327.107 us; speedup 1.0000x reference)
//
#include <hip/hip_runtime.h>
#include <hip/hip_bf16.h>

// TripletLoss N=8192, D=128. Round 6: 2-launch structure.
// Round-5 post-mortem: corr_kernel was 59us at 3% occupancy (512 serial
// 1-wave blocks, O(N) ballot scan each) and the 4-launch structure carries
// ~40us of fixed overhead. Fix:
//  (a) corr depends only on raw F/labels (f32 on-the-fly x2/dot; the
//      cancellation residual vs the bf16 main pass is ~1e-5 relative on a
//      0.2% correction -> ~1e-6 on the loss) so it fuses into prep's launch
//      as 512 extra blocks (256 thr: vectorized LDS-atomic label scan,
//      4 waves split the ~16 members).
//  (b) finalize fuses into pairs via per-row-tile tickets: last of the 16
//      j-split blocks for a row tile reduces its 64 rows; last of the 128
//      winners writes out[0]. threadfence+syncthreads+acq_rel agent atomics.
// Main-pass mining algebra unchanged: acc = dot - (x2i+x2j)/2 = -d2/2;
// nl += exp2(K1*s), ns += exp2(K1*s)*s with s = sqrt(d2/2), dist = sqrt2*s.

typedef __bf16 bf16x8 __attribute__((ext_vector_type(8)));
typedef float f32x4 __attribute__((ext_vector_type(4)));

#define NROWS 8192
#define DIM 128
#define JTILE 64
#define LDS_STRIDE 136    // 128 + 8 bf16 pad: 272B = 17 x 16B units (odd -> b128 conflict-free)
#define NLABELS 512
#define GCAP 64           // max rows per label group (E[gsz]=16, P(gsz>64) ~ 0)
#define PREP_BLOCKS (NROWS / 4)   // 2048
#define MARGIN_F 0.3f
#define SQRT2_F 1.41421356f
#define K1F (-2.04027892f)   // -sqrt2 * log2(e):  exp(-dist) = exp2(K1*s)
#define K2F ( 2.04027892f)   //  sqrt2 * log2(e)
#define C2F (-43.2808512f)   // -30 * log2(e):     exp(dist-30) = exp2(K2*s + C2)

// ---------------- kernel 1: prep role + corr role in one launch ----------
// Blocks [0, PREP_BLOCKS): bf16 cast + row norms + zero tickets/gstat.
// Blocks [PREP_BLOCKS, PREP_BLOCKS+NLABELS): per-label positive sums and
// same-label negative-mass corrections, from raw F/labels only.
__global__ __launch_bounds__(256) void prep_corr_kernel(
        const float* __restrict__ F,
        const int* __restrict__ labels,
        __hip_bfloat16* __restrict__ Fb,
        float* __restrict__ x2,
        float4* __restrict__ corr,
        int* __restrict__ ticket,       // [129]: per-bx tickets + final ticket
        float* __restrict__ gstat) {    // [2]: sum, cnt
    const int tid = threadIdx.x;
    if (blockIdx.x < PREP_BLOCKS) {
        // ---- prep role ----
        const int wave = tid >> 6, lane = tid & 63;
        const int row = blockIdx.x * 4 + wave;
        float2 f = ((const float2*)(F + (size_t)row * DIM))[lane];
        ((__hip_bfloat162*)(Fb + (size_t)row * DIM))[lane] = __float22bfloat162_rn(f);
        float ss = f.x * f.x + f.y * f.y;
#pragma unroll
        for (int m = 32; m > 0; m >>= 1) ss += __shfl_xor(ss, m, 64);
        if (lane == 0) x2[row] = ss;
        if (blockIdx.x == 0) {
            if (tid < 129) ticket[tid] = 0;
            if (tid < 2) gstat[tid] = 0.f;
        }
        return;
    }
    // ---- corr role: one block per label ----
    const int L = blockIdx.x - PREP_BLOCKS;
    __shared__ int sIdx[GCAP];
    __shared__ int sCnt;
    if (tid == 0) sCnt = 0;
    __syncthreads();
    for (int it = 0; it < NROWS / 1024; ++it) {          // 8 iterations
        const int g = it * 1024 + tid * 4;
        int4 lv = *(const int4*)(labels + g);
#pragma unroll
        for (int k = 0; k < 4; ++k) {
            int lab = (k == 0) ? lv.x : (k == 1) ? lv.y : (k == 2) ? lv.z : lv.w;
            if (lab == L) {
                int pos = atomicAdd(&sCnt, 1);
                if (pos < GCAP) sIdx[pos] = g + k;
            }
        }
    }
    __syncthreads();
    const int gsz = sCnt < GCAP ? sCnt : GCAP;
    if (gsz == 0) return;

    const int wave = tid >> 6, lane = tid & 63;
    const int b4 = lane >> 2;    // 16 b's in parallel
    const int cc = lane & 3;     // 4 x 32-dim chunks

    for (int aI = wave; aI < gsz; aI += 4) {
        const int ia = sIdx[aI];
        const float4* pa4 = (const float4*)(F + (size_t)ia * DIM + cc * 32);
        float4 va[8];
#pragma unroll
        for (int u = 0; u < 8; ++u) va[u] = pa4[u];
        float ssa = 0.f;
#pragma unroll
        for (int u = 0; u < 8; ++u)
            ssa += va[u].x * va[u].x + va[u].y * va[u].y +
                   va[u].z * va[u].z + va[u].w * va[u].w;
        ssa += __shfl_xor(ssa, 1, 64);
        ssa += __shfl_xor(ssa, 2, 64);          // x2[ia] on every lane

        float nl = 0.f, ns = 0.f, pl = 0.f, ps = 0.f;
        for (int bb = 0; bb < gsz; bb += 16) {
            const int b = bb + b4;
            const bool bv = (b < gsz) && (b != aI);
            const int ib = sIdx[b < gsz ? b : gsz - 1];
            const float4* pb4 = (const float4*)(F + (size_t)ib * DIM + cc * 32);
            float ssb = 0.f, dot = 0.f;
#pragma unroll
            for (int u = 0; u < 8; ++u) {
                float4 vb = pb4[u];
                ssb += vb.x * vb.x + vb.y * vb.y + vb.z * vb.z + vb.w * vb.w;
                dot = fmaf(va[u].x, vb.x, dot);
                dot = fmaf(va[u].y, vb.y, dot);
                dot = fmaf(va[u].z, vb.z, dot);
                dot = fmaf(va[u].w, vb.w, dot);
            }
            ssb += __shfl_xor(ssb, 1, 64); ssb += __shfl_xor(ssb, 2, 64);
            dot += __shfl_xor(dot, 1, 64); dot += __shfl_xor(dot, 2, 64);
            float d2h = fmaxf(0.5f * (ssa + ssb) - dot, 5e-9f);   // d2/2, clip
            float s = __builtin_amdgcn_sqrtf(d2h);
            float ne = __builtin_amdgcn_exp2f(K1F * s);
            float pe = __builtin_amdgcn_exp2f(fmaf(K2F, s, C2F));
            if (bv && cc == 0) {
                nl += ne; ns = fmaf(ne, s, ns);
                pl += pe; ps = fmaf(pe, s, ps);
            }
        }
        // sum the 16 cc==0 lanes (masks 4..32 keep cc fixed)
#pragma unroll
        for (int m = 4; m < 64; m <<= 1) {
            nl += __shfl_xor(nl, m, 64);
            ns += __shfl_xor(ns, m, 64);
            pl += __shfl_xor(pl, m, 64);
            ps += __shfl_xor(ps, m, 64);
        }
        if (lane == 0) corr[ia] = make_float4(pl, ps, -nl, -ns);
    }
}

// ---------------- kernel 2: fused GEMM + mining + last-block finalize ------
template<bool DIAG>
__device__ __forceinline__ void tile_body(const __hip_bfloat16* __restrict__ sB,
                                          const float* __restrict__ sX2h,
                                          const bf16x8* a, const float* x2ih,
                                          float (&nl4)[4], float (&ns4)[4],
                                          int lm, int quad, int ig0, int jbase) {
#pragma unroll
    for (int jt = 0; jt < 4; ++jt) {
        const int jl = jt * 16 + lm;
        const __hip_bfloat16* bp = sB + jl * LDS_STRIDE + quad * 8;
        const float xjh = sX2h[jl];
        f32x4 acc;
#pragma unroll
        for (int r = 0; r < 4; ++r) acc[r] = x2ih[r] + xjh;
#pragma unroll
        for (int kc = 0; kc < 4; ++kc) {
            bf16x8 b = *(const bf16x8*)(bp + kc * 32);
            acc = __builtin_amdgcn_mfma_f32_16x16x32_bf16(a[kc], b, acc, 0, 0, 0);
        }
        const int dj = jbase + jl - ig0;   // self-pair iff dj == r
#pragma unroll
        for (int r = 0; r < 4; ++r) {
            float d2h = fmaxf(-acc[r], 5e-9f);          // = d2/2, clip(1e-8)
            float s = __builtin_amdgcn_sqrtf(d2h);      // dist = sqrt2 * s
            float ne = __builtin_amdgcn_exp2f(K1F * s); // exp(-dist)
            if (DIAG) ne = (dj == r) ? 0.f : ne;
            nl4[r] += ne;
            ns4[r] = fmaf(ne, s, ns4[r]);
        }
    }
}

__global__ __launch_bounds__(256, 4) void pairs_fin_kernel(
        const __hip_bfloat16* __restrict__ Fb,
        const float* __restrict__ x2,
        const float4* __restrict__ corr,
        float2* __restrict__ partial,
        int* __restrict__ ticket,
        float* __restrict__ gstat,
        float* __restrict__ out,
        int jspan) {
    __shared__ __hip_bfloat16 sB[JTILE * LDS_STRIDE];
    __shared__ float sX2h[JTILE];     // -0.5 * x2j
    __shared__ int sWin;

    const int tid = threadIdx.x;
    const int wave = tid >> 6;
    const int lane = tid & 63;
    const int quad = lane >> 4;
    const int lm = lane & 15;
    const int rbase = blockIdx.x * 64 + wave * 16;

    bf16x8 a[4];
#pragma unroll
    for (int kc = 0; kc < 4; ++kc)
        a[kc] = *(const bf16x8*)(Fb + (size_t)(rbase + lm) * DIM + kc * 32 + quad * 8);

    // C/D layout: col(n)=lane&15 (j), row(m)=quad*4+r (i)
    const int ig0 = rbase + quad * 4;
    float x2ih[4];
#pragma unroll
    for (int r = 0; r < 4; ++r) x2ih[r] = -0.5f * x2[ig0 + r];

    float nl4[4] = {0,0,0,0}, ns4[4] = {0,0,0,0};

    const int j0 = blockIdx.y * jspan;
    const int jiters = jspan >> 6;
    const int djb = blockIdx.x - blockIdx.y * jiters;   // jb holding the diagonal

    for (int jb = 0; jb < jiters; ++jb) {
        const int jbase = j0 + jb * JTILE;
        __syncthreads();   // protect LDS from previous iteration's readers
#pragma unroll
        for (int s = 0; s < 4; ++s) {
            int c = tid + s * 256;
            int jr = c >> 4, ck = c & 15;
            *(bf16x8*)(sB + jr * LDS_STRIDE + ck * 8) =
                *(const bf16x8*)(Fb + (size_t)(jbase + jr) * DIM + ck * 8);
        }
        if (tid < JTILE) sX2h[tid] = -0.5f * x2[jbase + tid];
        __syncthreads();

        if (jb == djb)
            tile_body<true >(sB, sX2h, a, x2ih, nl4, ns4, lm, quad, ig0, jbase);
        else
            tile_body<false>(sB, sX2h, a, x2ih, nl4, ns4, lm, quad, ig0, jbase);
    }

    // reduce over the 16 lanes (lm) sharing each i-row
#pragma unroll
    for (int m = 1; m < 16; m <<= 1) {
#pragma unroll
        for (int r = 0; r < 4; ++r) {
            nl4[r] += __shfl_xor(nl4[r], m, 64);
            ns4[r] += __shfl_xor(ns4[r], m, 64);
        }
    }
    if (lm == 0) {
#pragma unroll
        for (int r = 0; r < 4; ++r)
            partial[(size_t)blockIdx.y * NROWS + ig0 + r] =
                make_float2(nl4[r], ns4[r]);
    }

    // ---- last j-split block for this row tile finalizes its 64 rows ----
    __threadfence();     // make this thread's partial stores device-visible
    __syncthreads();     // all threads' stores fenced before the ticket
    if (tid == 0) {
        int t = __hip_atomic_fetch_add(&ticket[blockIdx.x], 1,
                                       __ATOMIC_ACQ_REL, __HIP_MEMORY_SCOPE_AGENT);
        sWin = (t == (int)gridDim.y - 1);
    }
    __syncthreads();
    if (!sWin || tid >= 64) return;

    const int row = blockIdx.x * 64 + tid;
    float4 c = corr[row];
    float nl = c.z, ns = c.w;    // negative corrections (subtract same-label mass)
    for (int s = 0; s < (int)gridDim.y; ++s) {
        float2 p = partial[(size_t)s * NROWS + row];
        nl += p.x; ns += p.y;
    }
    float sum = 0.f, cnt = 0.f;
    if (c.x > 0.f && nl > 0.f) {
        float xx = fmaf(SQRT2_F, c.y / c.x - ns / nl, MARGIN_F);  // wp - wn + margin
        sum = fmaxf(xx, 0.f) + log1pf(__expf(-fabsf(xx)));        // stable softplus
        cnt = 1.f;
    }
#pragma unroll
    for (int m = 32; m > 0; m >>= 1) {
        sum += __shfl_xor(sum, m, 64);
        cnt += __shfl_xor(cnt, m, 64);
    }
    if (tid == 0) {
        unsafeAtomicAdd(&gstat[0], sum);
        unsafeAtomicAdd(&gstat[1], cnt);
        __threadfence();
        int t2 = __hip_atomic_fetch_add(&ticket[128], 1,
                                        __ATOMIC_ACQ_REL, __HIP_MEMORY_SCOPE_AGENT);
        if (t2 == (int)gridDim.x - 1) {
            float s2 = __hip_atomic_load(&gstat[0], __ATOMIC_ACQUIRE,
                                         __HIP_MEMORY_SCOPE_AGENT);
            float c2 = __hip_atomic_load(&gstat[1], __ATOMIC_ACQUIRE,
                                         __HIP_MEMORY_SCOPE_AGENT);
            out[0] = s2 / fmaxf(c2, 1.f);
        }
    }
}

extern "C" void kernel_launch(void* const* d_in, const int* in_sizes, int n_in,
                              void* d_out, int out_size, void* d_ws, size_t ws_size,
                              hipStream_t stream) {
    const float* F = (const float*)d_in[0];
    const int* labels = (const int*)d_in[1];
    float* out = (float*)d_out;

    char* ws = (char*)d_ws;
    __hip_bfloat16* Fb = (__hip_bfloat16*)ws;                       // 2 MB
    size_t off = (size_t)NROWS * DIM * 2;
    float* x2 = (float*)(ws + off);  off += (size_t)NROWS * 4;      // 32 KB
    float4* corr = (float4*)(ws + off);  off += (size_t)NROWS * 16; // 128 KB

    int jsplit = 16;
    while (jsplit > 1 && off + (size_t)jsplit * NROWS * 8 + 1024 > ws_size) jsplit >>= 1;
    float2* partial = (float2*)(ws + off);  off += (size_t)jsplit * NROWS * 8;
    int* ticket = (int*)(ws + off);                                 // 129 ints
    float* gstat = (float*)(ws + off + 132 * 4);                    // 2 floats

    prep_corr_kernel<<<PREP_BLOCKS + NLABELS, 256, 0, stream>>>(
        F, labels, Fb, x2, corr, ticket, gstat);
    pairs_fin_kernel<<<dim3(NROWS / 64, jsplit), 256, 0, stream>>>(
        Fb, x2, corr, partial, ticket, gstat, out, NROWS / jsplit);
}

// Round 5
// 153.521 us; speedup vs baseline: 2.1307x; 2.1307x over previous
//
#include <hip/hip_runtime.h>
#include <hip/hip_bf16.h>

// TripletLoss N=8192, D=128. Round 7: 3-launch, wide (128-row) pair blocks.
// Round-6 post-mortem: per-block __threadfence + ACQ_REL agent atomics in
// pairs_fin = 2048 full per-XCD L2 writeback/invalidate walks (gfx950 L2s
// are not cross-XCD coherent) -> 224us at 9% VALUBusy. Fix: finalize is a
// separate tiny kernel again (kernel boundary = free device-wide ordering).
// New: each pairs block covers 128 i-rows (32/wave, 2 MFMA row-groups that
// SHARE each LDS B-fragment read) -> global LDS read traffic halves, and
// 1024 blocks = exactly 4 resident blocks/CU at (256,4) in one pass.
//
// Mining algebra unchanged: MFMA C-init -(x2i+x2j)/2 so acc = -d2/2;
// s = sqrt(d2/2), dist = sqrt2*s; nl += exp2(K1*s), ns += exp2(K1*s)*s.
// Label-free main loop; per-label corr blocks (fused into prep's launch)
// subtract same-label negative mass and produce positive sums from raw F.

typedef __bf16 bf16x8 __attribute__((ext_vector_type(8)));
typedef float f32x4 __attribute__((ext_vector_type(4)));

#define NROWS 8192
#define DIM 128
#define JTILE 64
#define LDS_STRIDE 136    // 128 + 8 bf16 pad: 272B = 17 x 16B units (odd -> b128 conflict-free)
#define NLABELS 512
#define GCAP 64           // max rows per label group (E[gsz]=16, P(gsz>64) ~ 0)
#define PREP_BLOCKS (NROWS / 4)   // 2048
#define MARGIN_F 0.3f
#define SQRT2_F 1.41421356f
#define K1F (-2.04027892f)   // -sqrt2 * log2(e):  exp(-dist) = exp2(K1*s)
#define K2F ( 2.04027892f)   //  sqrt2 * log2(e)
#define C2F (-43.2808512f)   // -30 * log2(e):     exp(dist-30) = exp2(K2*s + C2)

// ---------------- kernel 1: prep role + corr role in one launch ----------
__global__ __launch_bounds__(256) void prep_corr_kernel(
        const float* __restrict__ F,
        const int* __restrict__ labels,
        __hip_bfloat16* __restrict__ Fb,
        float* __restrict__ x2,
        float4* __restrict__ corr,
        float* __restrict__ gstat) {    // [4]: sum, cnt, ticket, pad
    const int tid = threadIdx.x;
    if (blockIdx.x < PREP_BLOCKS) {
        // ---- prep role: bf16 cast + row norms ----
        const int wave = tid >> 6, lane = tid & 63;
        const int row = blockIdx.x * 4 + wave;
        float2 f = ((const float2*)(F + (size_t)row * DIM))[lane];
        ((__hip_bfloat162*)(Fb + (size_t)row * DIM))[lane] = __float22bfloat162_rn(f);
        float ss = f.x * f.x + f.y * f.y;
#pragma unroll
        for (int m = 32; m > 0; m >>= 1) ss += __shfl_xor(ss, m, 64);
        if (lane == 0) x2[row] = ss;
        if (blockIdx.x == 0 && tid < 4) gstat[tid] = 0.f;
        return;
    }
    // ---- corr role: one block per label ----
    const int L = blockIdx.x - PREP_BLOCKS;
    __shared__ int sIdx[GCAP];
    __shared__ int sCnt;
    if (tid == 0) sCnt = 0;
    __syncthreads();
    for (int it = 0; it < NROWS / 1024; ++it) {          // 8 iterations
        const int g = it * 1024 + tid * 4;
        int4 lv = *(const int4*)(labels + g);
#pragma unroll
        for (int k = 0; k < 4; ++k) {
            int lab = (k == 0) ? lv.x : (k == 1) ? lv.y : (k == 2) ? lv.z : lv.w;
            if (lab == L) {
                int pos = atomicAdd(&sCnt, 1);
                if (pos < GCAP) sIdx[pos] = g + k;
            }
        }
    }
    __syncthreads();
    const int gsz = sCnt < GCAP ? sCnt : GCAP;
    if (gsz == 0) return;

    const int wave = tid >> 6, lane = tid & 63;
    const int b4 = lane >> 2;    // 16 b's in parallel
    const int cc = lane & 3;     // 4 x 32-dim chunks

    for (int aI = wave; aI < gsz; aI += 4) {
        const int ia = sIdx[aI];
        const float4* pa4 = (const float4*)(F + (size_t)ia * DIM + cc * 32);
        float4 va[8];
#pragma unroll
        for (int u = 0; u < 8; ++u) va[u] = pa4[u];
        float ssa = 0.f;
#pragma unroll
        for (int u = 0; u < 8; ++u)
            ssa += va[u].x * va[u].x + va[u].y * va[u].y +
                   va[u].z * va[u].z + va[u].w * va[u].w;
        ssa += __shfl_xor(ssa, 1, 64);
        ssa += __shfl_xor(ssa, 2, 64);          // x2[ia] on every lane

        float nl = 0.f, ns = 0.f, pl = 0.f, ps = 0.f;
        for (int bb = 0; bb < gsz; bb += 16) {
            const int b = bb + b4;
            const bool bv = (b < gsz) && (b != aI);
            const int ib = sIdx[b < gsz ? b : gsz - 1];
            const float4* pb4 = (const float4*)(F + (size_t)ib * DIM + cc * 32);
            float ssb = 0.f, dot = 0.f;
#pragma unroll
            for (int u = 0; u < 8; ++u) {
                float4 vb = pb4[u];
                ssb += vb.x * vb.x + vb.y * vb.y + vb.z * vb.z + vb.w * vb.w;
                dot = fmaf(va[u].x, vb.x, dot);
                dot = fmaf(va[u].y, vb.y, dot);
                dot = fmaf(va[u].z, vb.z, dot);
                dot = fmaf(va[u].w, vb.w, dot);
            }
            ssb += __shfl_xor(ssb, 1, 64); ssb += __shfl_xor(ssb, 2, 64);
            dot += __shfl_xor(dot, 1, 64); dot += __shfl_xor(dot, 2, 64);
            float d2h = fmaxf(0.5f * (ssa + ssb) - dot, 5e-9f);   // d2/2, clip
            float s = __builtin_amdgcn_sqrtf(d2h);
            float ne = __builtin_amdgcn_exp2f(K1F * s);
            float pe = __builtin_amdgcn_exp2f(fmaf(K2F, s, C2F));
            if (bv && cc == 0) {
                nl += ne; ns = fmaf(ne, s, ns);
                pl += pe; ps = fmaf(pe, s, ps);
            }
        }
        // sum the 16 cc==0 lanes (masks 4..32 keep cc fixed)
#pragma unroll
        for (int m = 4; m < 64; m <<= 1) {
            nl += __shfl_xor(nl, m, 64);
            ns += __shfl_xor(ns, m, 64);
            pl += __shfl_xor(pl, m, 64);
            ps += __shfl_xor(ps, m, 64);
        }
        if (lane == 0) corr[ia] = make_float4(pl, ps, -nl, -ns);
    }
}

// ---------------- kernel 2: fused GEMM + unmasked negative mining ----------
// 128 i-rows per block: 32 per wave as 2 row-groups (g) of 16; each LDS
// B-fragment read feeds both groups' MFMAs (halves LDS read traffic).
template<bool DIAG>
__device__ __forceinline__ void tile_body(const __hip_bfloat16* __restrict__ sB,
                                          const float* __restrict__ sX2h,
                                          const bf16x8 (&a)[2][4],
                                          const float (&x2ih)[2][4],
                                          float (&nl)[2][4], float (&ns)[2][4],
                                          int lm, int quad, int ibase, int jbase) {
#pragma unroll
    for (int jt = 0; jt < 4; ++jt) {
        const int jl = jt * 16 + lm;
        const __hip_bfloat16* bp = sB + jl * LDS_STRIDE + quad * 8;
        bf16x8 b[4];
#pragma unroll
        for (int kc = 0; kc < 4; ++kc) b[kc] = *(const bf16x8*)(bp + kc * 32);
        const float xjh = sX2h[jl];
#pragma unroll
        for (int g = 0; g < 2; ++g) {
            f32x4 acc;
#pragma unroll
            for (int r = 0; r < 4; ++r) acc[r] = x2ih[g][r] + xjh;
#pragma unroll
            for (int kc = 0; kc < 4; ++kc)
                acc = __builtin_amdgcn_mfma_f32_16x16x32_bf16(a[g][kc], b[kc], acc, 0, 0, 0);
            // self-pair: jglob == iglob  <=>  djg == r
            const int djg = jbase + jl - (ibase + g * 16 + quad * 4);
#pragma unroll
            for (int r = 0; r < 4; ++r) {
                float d2h = fmaxf(-acc[r], 5e-9f);          // = d2/2, clip(1e-8)
                float s = __builtin_amdgcn_sqrtf(d2h);      // dist = sqrt2 * s
                float ne = __builtin_amdgcn_exp2f(K1F * s); // exp(-dist)
                if (DIAG) ne = (djg == r) ? 0.f : ne;
                nl[g][r] += ne;
                ns[g][r] = fmaf(ne, s, ns[g][r]);
            }
        }
    }
}

__global__ __launch_bounds__(256, 4) void pairs_kernel(
        const __hip_bfloat16* __restrict__ Fb,
        const float* __restrict__ x2,
        float2* __restrict__ partial,
        int jspan) {
    __shared__ __hip_bfloat16 sB[JTILE * LDS_STRIDE];
    __shared__ float sX2h[JTILE];     // -0.5 * x2j

    const int tid = threadIdx.x;
    const int wave = tid >> 6;
    const int lane = tid & 63;
    const int quad = lane >> 4;
    const int lm = lane & 15;
    const int ibase = blockIdx.x * 128 + wave * 32;

    // A fragments: 2 row-groups x 4 k-chunks, kept for the whole j loop.
    bf16x8 a[2][4];
#pragma unroll
    for (int g = 0; g < 2; ++g)
#pragma unroll
        for (int kc = 0; kc < 4; ++kc)
            a[g][kc] = *(const bf16x8*)(Fb + (size_t)(ibase + g * 16 + lm) * DIM
                                        + kc * 32 + quad * 8);

    // C/D layout: col(n)=lane&15 (j), row(m)=quad*4+r (i)
    float x2ih[2][4];
#pragma unroll
    for (int g = 0; g < 2; ++g)
#pragma unroll
        for (int r = 0; r < 4; ++r)
            x2ih[g][r] = -0.5f * x2[ibase + g * 16 + quad * 4 + r];

    float nl[2][4] = {}, ns[2][4] = {};

    const int j0 = blockIdx.y * jspan;
    const int jiters = jspan >> 6;
    // block's i-range spans global 64-col tiles 2*bx and 2*bx+1
    const int djb0 = 2 * (int)blockIdx.x - (int)blockIdx.y * jiters;

    for (int jb = 0; jb < jiters; ++jb) {
        const int jbase = j0 + jb * JTILE;
        __syncthreads();   // protect LDS from previous iteration's readers
#pragma unroll
        for (int s = 0; s < 4; ++s) {
            int c = tid + s * 256;
            int jr = c >> 4, ck = c & 15;
            *(bf16x8*)(sB + jr * LDS_STRIDE + ck * 8) =
                *(const bf16x8*)(Fb + (size_t)(jbase + jr) * DIM + ck * 8);
        }
        if (tid < JTILE) sX2h[tid] = -0.5f * x2[jbase + tid];
        __syncthreads();

        if ((unsigned)(jb - djb0) <= 1u)
            tile_body<true >(sB, sX2h, a, x2ih, nl, ns, lm, quad, ibase, jbase);
        else
            tile_body<false>(sB, sX2h, a, x2ih, nl, ns, lm, quad, ibase, jbase);
    }

    // reduce over the 16 lanes (lm) sharing each i-row
#pragma unroll
    for (int m = 1; m < 16; m <<= 1) {
#pragma unroll
        for (int g = 0; g < 2; ++g)
#pragma unroll
            for (int r = 0; r < 4; ++r) {
                nl[g][r] += __shfl_xor(nl[g][r], m, 64);
                ns[g][r] += __shfl_xor(ns[g][r], m, 64);
            }
    }
    if (lm == 0) {
#pragma unroll
        for (int g = 0; g < 2; ++g)
#pragma unroll
            for (int r = 0; r < 4; ++r)
                partial[(size_t)blockIdx.y * NROWS + ibase + g * 16 + quad * 4 + r] =
                    make_float2(nl[g][r], ns[g][r]);
    }
}

// ---------------- kernel 3: per-row loss, reduce, final divide -------------
__global__ __launch_bounds__(256) void finalize_kernel(const float2* __restrict__ partial,
                                                       const float4* __restrict__ corr,
                                                       float* __restrict__ gstat,
                                                       float* __restrict__ out,
                                                       int jsplit) {
    const int row = blockIdx.x * 256 + threadIdx.x;
    float4 c = corr[row];
    float nl = c.z, ns = c.w;    // negative corrections (subtract same-label mass)
    for (int s = 0; s < jsplit; ++s) {
        float2 p = partial[(size_t)s * NROWS + row];
        nl += p.x; ns += p.y;
    }
    float sum = 0.f, cnt = 0.f;
    if (c.x > 0.f && nl > 0.f) {
        float x = fmaf(SQRT2_F, c.y / c.x - ns / nl, MARGIN_F);  // wp - wn + margin
        sum = fmaxf(x, 0.f) + log1pf(__expf(-fabsf(x)));         // stable softplus
        cnt = 1.f;
    }
#pragma unroll
    for (int m = 32; m > 0; m >>= 1) {
        sum += __shfl_xor(sum, m, 64);
        cnt += __shfl_xor(cnt, m, 64);
    }
    __shared__ float sS[4], sC[4];
    const int wave = threadIdx.x >> 6, lane = threadIdx.x & 63;
    if (lane == 0) { sS[wave] = sum; sC[wave] = cnt; }
    __syncthreads();
    if (threadIdx.x == 0) {
        unsafeAtomicAdd(&gstat[0], sS[0] + sS[1] + sS[2] + sS[3]);
        unsafeAtomicAdd(&gstat[1], sC[0] + sC[1] + sC[2] + sC[3]);
        __threadfence();
        unsigned t = atomicAdd((unsigned int*)(gstat + 2), 1u);
        if (t == (unsigned)(gridDim.x - 1)) {
            float s2 = unsafeAtomicAdd(&gstat[0], 0.f);   // L2 reads
            float c2 = unsafeAtomicAdd(&gstat[1], 0.f);
            out[0] = s2 / fmaxf(c2, 1.f);
        }
    }
}

extern "C" void kernel_launch(void* const* d_in, const int* in_sizes, int n_in,
                              void* d_out, int out_size, void* d_ws, size_t ws_size,
                              hipStream_t stream) {
    const float* F = (const float*)d_in[0];
    const int* labels = (const int*)d_in[1];
    float* out = (float*)d_out;

    char* ws = (char*)d_ws;
    __hip_bfloat16* Fb = (__hip_bfloat16*)ws;                       // 2 MB
    size_t off = (size_t)NROWS * DIM * 2;
    float* x2 = (float*)(ws + off);  off += (size_t)NROWS * 4;      // 32 KB
    float4* corr = (float4*)(ws + off);  off += (size_t)NROWS * 16; // 128 KB

    int jsplit = 16;
    while (jsplit > 1 && off + (size_t)jsplit * NROWS * 8 + 64 > ws_size) jsplit >>= 1;
    float2* partial = (float2*)(ws + off);  off += (size_t)jsplit * NROWS * 8;
    float* gstat = (float*)(ws + off);                              // 4 floats

    prep_corr_kernel<<<PREP_BLOCKS + NLABELS, 256, 0, stream>>>(
        F, labels, Fb, x2, corr, gstat);
    pairs_kernel<<<dim3(NROWS / 128, jsplit), 256, 0, stream>>>(
        Fb, x2, partial, NROWS / jsplit);
    finalize_kernel<<<NROWS / 256, 256, 0, stream>>>(partial, corr, gstat, out, jsplit);
}

// Round 6
// 120.234 us; speedup vs baseline: 2.7206x; 1.2769x over previous
//
#include <hip/hip_runtime.h>
#include <hip/hip_bf16.h>

// TripletLoss N=8192, D=128. Round 8: bucketed corr fused into pairs launch.
// Round-7 post-mortem: the 512 corr blocks (per-label O(N) label scan +
// scattered member loads at 1-2 blocks/CU) were latency-bound at 70-80us in
// BOTH the 1-wave (r5: 59us) and 4-wave (r7: 75us) variants. Fix: remove
// both invariants. prep builds label->rows buckets via global atomics
// (gcnt/gslot, memset-zeroed); corr becomes one-THREAD-per-same-label-pair
// (131K pairs, bf16 dot from L2-hot Fb, LDS-atomic per-row sums), run as a
// tail on the by<=1 pairs blocks so it overlaps the 55us pairs phase and
// adds no extra blocks past the 1024-resident limit.
//
// Mining algebra unchanged: MFMA C-init -(x2i+x2j)/2 so acc = -d2/2;
// s = sqrt(d2/2), dist = sqrt2*s; nl += exp2(K1*s), ns += exp2(K1*s)*s over
// ALL j!=i (label-free); corr subtracts same-label negative mass and
// produces positive sums pl/ps = sum exp2(K2*s+C2)[*s].

typedef __bf16 bf16x8 __attribute__((ext_vector_type(8)));
typedef float f32x4 __attribute__((ext_vector_type(4)));

#define NROWS 8192
#define DIM 128
#define JTILE 64
#define LDS_STRIDE 136    // 128 + 8 bf16 pad: 272B = 17 x 16B units (odd -> b128 conflict-free)
#define NLABELS 512
#define GCAP 64           // max rows per label (E=16, sigma~4; P(>64) ~ 1e-30)
#define MARGIN_F 0.3f
#define SQRT2_F 1.41421356f
#define K1F (-2.04027892f)   // -sqrt2 * log2(e):  exp(-dist) = exp2(K1*s)
#define K2F ( 2.04027892f)   //  sqrt2 * log2(e)
#define C2F (-43.2808512f)   // -30 * log2(e):     exp(dist-30) = exp2(K2*s + C2)

// ---------------- kernel 1: bf16 cast + row norms + label buckets ----------
__global__ __launch_bounds__(256) void prep_kernel(const float* __restrict__ F,
                                                   const int* __restrict__ labels,
                                                   __hip_bfloat16* __restrict__ Fb,
                                                   float* __restrict__ x2,
                                                   int* __restrict__ gcnt,
                                                   int* __restrict__ gslot) {
    const int tid = threadIdx.x;
    const int wave = tid >> 6, lane = tid & 63;
    const int row = blockIdx.x * 4 + wave;
    float2 f = ((const float2*)(F + (size_t)row * DIM))[lane];
    ((__hip_bfloat162*)(Fb + (size_t)row * DIM))[lane] = __float22bfloat162_rn(f);
    float ss = f.x * f.x + f.y * f.y;
#pragma unroll
    for (int m = 32; m > 0; m >>= 1) ss += __shfl_xor(ss, m, 64);
    if (lane == 0) {
        x2[row] = ss;
        const int lab = labels[row];
        int pos = atomicAdd(&gcnt[lab], 1);
        if (pos < GCAP) gslot[lab * GCAP + pos] = row;
    }
}

// ---------------- kernel 2: fused GEMM + mining, corr tail on by<=1 --------
// 128 i-rows per block: 32 per wave as 2 row-groups sharing each LDS B read.
template<bool DIAG>
__device__ __forceinline__ void tile_body(const __hip_bfloat16* __restrict__ sB,
                                          const float* __restrict__ sX2h,
                                          const bf16x8 (&a)[2][4],
                                          const float (&x2ih)[2][4],
                                          float (&nl)[2][4], float (&ns)[2][4],
                                          int lm, int quad, int ibase, int jbase) {
#pragma unroll
    for (int jt = 0; jt < 4; ++jt) {
        const int jl = jt * 16 + lm;
        const __hip_bfloat16* bp = sB + jl * LDS_STRIDE + quad * 8;
        bf16x8 b[4];
#pragma unroll
        for (int kc = 0; kc < 4; ++kc) b[kc] = *(const bf16x8*)(bp + kc * 32);
        const float xjh = sX2h[jl];
#pragma unroll
        for (int g = 0; g < 2; ++g) {
            f32x4 acc;
#pragma unroll
            for (int r = 0; r < 4; ++r) acc[r] = x2ih[g][r] + xjh;
#pragma unroll
            for (int kc = 0; kc < 4; ++kc)
                acc = __builtin_amdgcn_mfma_f32_16x16x32_bf16(a[g][kc], b[kc], acc, 0, 0, 0);
            const int djg = jbase + jl - (ibase + g * 16 + quad * 4);  // self iff == r
#pragma unroll
            for (int r = 0; r < 4; ++r) {
                float d2h = fmaxf(-acc[r], 5e-9f);          // = d2/2, clip(1e-8)
                float s = __builtin_amdgcn_sqrtf(d2h);      // dist = sqrt2 * s
                float ne = __builtin_amdgcn_exp2f(K1F * s); // exp(-dist)
                if (DIAG) ne = (djg == r) ? 0.f : ne;
                nl[g][r] += ne;
                ns[g][r] = fmaf(ne, s, ns[g][r]);
            }
        }
    }
}

__global__ __launch_bounds__(256, 4) void pairs_kernel(
        const __hip_bfloat16* __restrict__ Fb,
        const float* __restrict__ x2,
        const int* __restrict__ gcnt,
        const int* __restrict__ gslot,
        float2* __restrict__ partial,
        float4* __restrict__ corr,
        int jspan) {
    __shared__ __hip_bfloat16 sB[JTILE * LDS_STRIDE];
    __shared__ float sX2h[JTILE];     // -0.5 * x2j

    const int tid = threadIdx.x;
    const int wave = tid >> 6;
    const int lane = tid & 63;
    const int quad = lane >> 4;
    const int lm = lane & 15;
    const int ibase = blockIdx.x * 128 + wave * 32;

    bf16x8 a[2][4];
#pragma unroll
    for (int g = 0; g < 2; ++g)
#pragma unroll
        for (int kc = 0; kc < 4; ++kc)
            a[g][kc] = *(const bf16x8*)(Fb + (size_t)(ibase + g * 16 + lm) * DIM
                                        + kc * 32 + quad * 8);

    // C/D layout: col(n)=lane&15 (j), row(m)=quad*4+r (i)
    float x2ih[2][4];
#pragma unroll
    for (int g = 0; g < 2; ++g)
#pragma unroll
        for (int r = 0; r < 4; ++r)
            x2ih[g][r] = -0.5f * x2[ibase + g * 16 + quad * 4 + r];

    float nl[2][4] = {}, ns[2][4] = {};

    const int j0 = blockIdx.y * jspan;
    const int jiters = jspan >> 6;
    const int djb0 = 2 * (int)blockIdx.x - (int)blockIdx.y * jiters;

    for (int jb = 0; jb < jiters; ++jb) {
        const int jbase = j0 + jb * JTILE;
        __syncthreads();   // protect LDS from previous iteration's readers
#pragma unroll
        for (int s = 0; s < 4; ++s) {
            int c = tid + s * 256;
            int jr = c >> 4, ck = c & 15;
            *(bf16x8*)(sB + jr * LDS_STRIDE + ck * 8) =
                *(const bf16x8*)(Fb + (size_t)(jbase + jr) * DIM + ck * 8);
        }
        if (tid < JTILE) sX2h[tid] = -0.5f * x2[jbase + tid];
        __syncthreads();

        if ((unsigned)(jb - djb0) <= 1u)
            tile_body<true >(sB, sX2h, a, x2ih, nl, ns, lm, quad, ibase, jbase);
        else
            tile_body<false>(sB, sX2h, a, x2ih, nl, ns, lm, quad, ibase, jbase);
    }

    // reduce over the 16 lanes (lm) sharing each i-row
#pragma unroll
    for (int m = 1; m < 16; m <<= 1) {
#pragma unroll
        for (int g = 0; g < 2; ++g)
#pragma unroll
            for (int r = 0; r < 4; ++r) {
                nl[g][r] += __shfl_xor(nl[g][r], m, 64);
                ns[g][r] += __shfl_xor(ns[g][r], m, 64);
            }
    }
    if (lm == 0) {
#pragma unroll
        for (int g = 0; g < 2; ++g)
#pragma unroll
            for (int r = 0; r < 4; ++r)
                partial[(size_t)blockIdx.y * NROWS + ibase + g * 16 + quad * 4 + r] =
                    make_float2(nl[g][r], ns[g][r]);
    }

    // ---- corr tail: 128 blocks (by<=1) x 4 labels, one thread per pair ----
    if (blockIdx.y > 1) return;
    __syncthreads();                       // done with sB as B-tile
    float* sAcc = (float*)sB;              // overlay: 4 x GCAP floats
    float* plA = sAcc;
    float* psA = sAcc + GCAP;
    float* nlA = sAcc + 2 * GCAP;
    float* nsA = sAcc + 3 * GCAP;
    const int cid = (int)blockIdx.x * 2 + (int)blockIdx.y;   // [0,128)

    for (int li = 0; li < NLABELS / 128; ++li) {             // 4 labels
        const int L = cid * (NLABELS / 128) + li;
        const int cnt = gcnt[L];
        const int gsz = cnt < GCAP ? cnt : GCAP;
        if (tid < GCAP) { plA[tid] = 0.f; psA[tid] = 0.f; nlA[tid] = 0.f; nsA[tid] = 0.f; }
        __syncthreads();
        const int npair = gsz * gsz;
        for (int p = tid; p < npair; p += 256) {
            const int aI = p / gsz, bI = p - aI * gsz;
            if (aI != bI) {
                const int ia = gslot[L * GCAP + aI];
                const int ib = gslot[L * GCAP + bI];
                const bf16x8* pa = (const bf16x8*)(Fb + (size_t)ia * DIM);
                const bf16x8* pb = (const bf16x8*)(Fb + (size_t)ib * DIM);
                float dot = 0.f;
#pragma unroll 4
                for (int u = 0; u < 16; ++u) {
                    bf16x8 va = pa[u], vb = pb[u];
#pragma unroll
                    for (int e = 0; e < 8; ++e)
                        dot = fmaf((float)va[e], (float)vb[e], dot);
                }
                float d2h = fmaxf(0.5f * (x2[ia] + x2[ib]) - dot, 5e-9f);  // = d2/2
                float s = __builtin_amdgcn_sqrtf(d2h);
                float ne = __builtin_amdgcn_exp2f(K1F * s);
                float pe = __builtin_amdgcn_exp2f(fmaf(K2F, s, C2F));
                unsafeAtomicAdd(&nlA[aI], ne);
                unsafeAtomicAdd(&nsA[aI], ne * s);
                unsafeAtomicAdd(&plA[aI], pe);
                unsafeAtomicAdd(&psA[aI], pe * s);
            }
        }
        __syncthreads();
        if (tid < gsz)
            corr[gslot[L * GCAP + tid]] =
                make_float4(plA[tid], psA[tid], -nlA[tid], -nsA[tid]);
        __syncthreads();                   // before reusing sAcc for next label
    }
}

// ---------------- kernel 3: per-row loss, reduce, final divide -------------
__global__ __launch_bounds__(256) void finalize_kernel(const float2* __restrict__ partial,
                                                       const float4* __restrict__ corr,
                                                       float* __restrict__ gstat,
                                                       float* __restrict__ out,
                                                       int jsplit) {
    const int row = blockIdx.x * 256 + threadIdx.x;
    float4 c = corr[row];
    float nl = c.z, ns = c.w;    // negative corrections (subtract same-label mass)
    for (int s = 0; s < jsplit; ++s) {
        float2 p = partial[(size_t)s * NROWS + row];
        nl += p.x; ns += p.y;
    }
    float sum = 0.f, cnt = 0.f;
    if (c.x > 0.f && nl > 0.f) {
        float x = fmaf(SQRT2_F, c.y / c.x - ns / nl, MARGIN_F);  // wp - wn + margin
        sum = fmaxf(x, 0.f) + log1pf(__expf(-fabsf(x)));         // stable softplus
        cnt = 1.f;
    }
#pragma unroll
    for (int m = 32; m > 0; m >>= 1) {
        sum += __shfl_xor(sum, m, 64);
        cnt += __shfl_xor(cnt, m, 64);
    }
    __shared__ float sS[4], sC[4];
    const int wave = threadIdx.x >> 6, lane = threadIdx.x & 63;
    if (lane == 0) { sS[wave] = sum; sC[wave] = cnt; }
    __syncthreads();
    if (threadIdx.x == 0) {
        unsafeAtomicAdd(&gstat[0], sS[0] + sS[1] + sS[2] + sS[3]);
        unsafeAtomicAdd(&gstat[1], sC[0] + sC[1] + sC[2] + sC[3]);
        __threadfence();
        unsigned t = atomicAdd((unsigned int*)(gstat + 2), 1u);
        if (t == (unsigned)(gridDim.x - 1)) {
            float s2 = unsafeAtomicAdd(&gstat[0], 0.f);   // L2 reads
            float c2 = unsafeAtomicAdd(&gstat[1], 0.f);
            out[0] = s2 / fmaxf(c2, 1.f);
        }
    }
}

extern "C" void kernel_launch(void* const* d_in, const int* in_sizes, int n_in,
                              void* d_out, int out_size, void* d_ws, size_t ws_size,
                              hipStream_t stream) {
    const float* F = (const float*)d_in[0];
    const int* labels = (const int*)d_in[1];
    float* out = (float*)d_out;

    char* ws = (char*)d_ws;
    __hip_bfloat16* Fb = (__hip_bfloat16*)ws;                        // 2 MB
    size_t off = (size_t)NROWS * DIM * 2;
    float* x2 = (float*)(ws + off);   off += (size_t)NROWS * 4;      // 32 KB
    float4* corr = (float4*)(ws + off); off += (size_t)NROWS * 16;   // 128 KB
    int* gcnt = (int*)(ws + off);     off += (size_t)NLABELS * 4;    // 2 KB
    float* gstat = (float*)(ws + off); off += 16;                    // 16 B
    int* gslot = (int*)(ws + off);    off += (size_t)NLABELS * GCAP * 4;  // 128 KB

    int jsplit = 16;
    while (jsplit > 2 && off + (size_t)jsplit * NROWS * 8 > ws_size) jsplit >>= 1;
    float2* partial = (float2*)(ws + off);

    // zero gcnt (512 ints) + gstat (4 floats) — contiguous region
    hipMemsetAsync(gcnt, 0, (size_t)NLABELS * 4 + 16, stream);
    prep_kernel<<<NROWS / 4, 256, 0, stream>>>(F, labels, Fb, x2, gcnt, gslot);
    pairs_kernel<<<dim3(NROWS / 128, jsplit), 256, 0, stream>>>(
        Fb, x2, gcnt, gslot, partial, corr, NROWS / jsplit);
    finalize_kernel<<<NROWS / 256, 256, 0, stream>>>(partial, corr, gstat, out, jsplit);
}